// Round 6
// baseline (207.689 us; speedup 1.0000x reference)
//
#include <hip/hip_runtime.h>
#include <math.h>

#define N_NODES 50000
#define N_EDGES 800000
#define BATCHES 128
#define DIM 64
#define HID 128
#define NCLS 2
#define EPSV 1e-5f
#define MAXD 64                                   // CSR slot planes

#define NBLK 782                                  // mega grid: 1 tile/block
#define EPB  1024                                 // edges per block (4/thread)

#define MREP 4                                    // stat accumulator replicas
#define MSTRIDE 32                                // floats between entries (128B)
#define BAR_STRIDE 512                            // uints per barrier struct (2KB)

typedef __attribute__((ext_vector_type(8))) short bf16x8;
typedef __attribute__((ext_vector_type(4))) float f32x4;

// ---- fp32 -> bf16 hi/lo split helpers ----
__device__ __forceinline__ unsigned short f2bf(float f){
  unsigned u = __float_as_uint(f);
  u += 0x7FFFu + ((u >> 16) & 1u);     // RNE
  return (unsigned short)(u >> 16);
}
__device__ __forceinline__ float bf2f(unsigned short h){
  return __uint_as_float(((unsigned)h) << 16);
}
__device__ __forceinline__ void split2(float f, unsigned short& hi, unsigned short& lo){
  hi = f2bf(f);
  lo = f2bf(f - bf2f(hi));
}
__device__ __forceinline__ uint4 pack8(const unsigned short* s){
  uint4 u;
  u.x = (unsigned)s[0] | ((unsigned)s[1] << 16);
  u.y = (unsigned)s[2] | ((unsigned)s[3] << 16);
  u.z = (unsigned)s[4] | ((unsigned)s[5] << 16);
  u.w = (unsigned)s[6] | ((unsigned)s[7] << 16);
  return u;
}

// ---- agent-scope (LLC-coherent) access: cross-XCD safe, bypasses L1/L2 ----
__device__ __forceinline__ float gload(const float* p){
  return __hip_atomic_load(p, __ATOMIC_RELAXED, __HIP_MEMORY_SCOPE_AGENT);
}
__device__ __forceinline__ int iload(const int* p){
  return __hip_atomic_load(p, __ATOMIC_RELAXED, __HIP_MEMORY_SCOPE_AGENT);
}
__device__ __forceinline__ unsigned uload(const unsigned* p){
  return __hip_atomic_load(p, __ATOMIC_RELAXED, __HIP_MEMORY_SCOPE_AGENT);
}
__device__ __forceinline__ void ustore(unsigned* p, unsigned v){
  __hip_atomic_store(p, v, __ATOMIC_RELAXED, __HIP_MEMORY_SCOPE_AGENT);
}

// ---- relaxed-only tree grid barrier: NO fences, NO L2 invalidates.
// All cross-barrier data moves via device-scope atomics / agent-scope
// atomic stores (performed at LLC) and agent-scope atomic loads.
__device__ __forceinline__ void gbar(unsigned* bb, int bx){
  __syncthreads();                       // drains vmcnt: prior ops ACKed @LLC
  if (threadIdx.x == 0){
    const int k = bx & 7;
    const unsigned quota = (k < (NBLK & 7)) ? (unsigned)(NBLK/8 + 1)
                                            : (unsigned)(NBLK/8);
    unsigned old = __hip_atomic_fetch_add(&bb[k*32], 1u,
                     __ATOMIC_RELAXED, __HIP_MEMORY_SCOPE_AGENT);
    if (old == quota - 1u){
      unsigned r = __hip_atomic_fetch_add(&bb[8*32], 1u,
                     __ATOMIC_RELAXED, __HIP_MEMORY_SCOPE_AGENT);
      if (r == 7u)
        __hip_atomic_store(&bb[9*32], 1u,
                     __ATOMIC_RELAXED, __HIP_MEMORY_SCOPE_AGENT);
    }
    while (__hip_atomic_load(&bb[9*32],
                     __ATOMIC_RELAXED, __HIP_MEMORY_SCOPE_AGENT) == 0u)
      __builtin_amdgcn_s_sleep(32);
  }
  asm volatile("" ::: "memory");         // compiler barrier (no instructions)
  __syncthreads();
}

// helper: stage one 64x64 weight transposed as bf16 hi/lo into [64][72] rows
__device__ __forceinline__ void stage_w64(short* sWh, short* sWl_,
                                          const float* __restrict__ W,
                                          int w, int lane){
  const int k0 = 16 * w;
  #pragma unroll
  for (int kc = 0; kc < 2; ++kc){
    unsigned short h[8], l[8];
    #pragma unroll
    for (int i = 0; i < 8; ++i){
      int k = k0 + 8*kc + i;
      split2(W[k*DIM + lane], h[i], l[i]);
    }
    *(uint4*)&sWh[lane*72 + k0 + 8*kc] = pack8(h);
    *(uint4*)&sWl_[lane*72 + k0 + 8*kc] = pack8(l);
  }
}

// 64-wide-K split-bf16 GEMM: ACC += A(64x64 from sA) @ B(64x64 from sB)^T
#define GEMM64(ACC) do { \
  _Pragma("unroll") \
  for (int kt2 = 0; kt2 < 2; ++kt2){ \
    const int ka = kt2*32 + koff; \
    bf16x8 ah = *(const bf16x8*)&sA[0][mrow][ka]; \
    bf16x8 al = *(const bf16x8*)&sA[1][mrow][ka]; \
    _Pragma("unroll") \
    for (int nt = 0; nt < 4; ++nt){ \
      const int nr = nt*16 + jc; \
      bf16x8 bh = *(const bf16x8*)&sB[0][nr][ka]; \
      bf16x8 bo = *(const bf16x8*)&sB[1][nr][ka]; \
      ACC[nt] = __builtin_amdgcn_mfma_f32_16x16x32_bf16(ah, bh, ACC[nt], 0,0,0); \
      ACC[nt] = __builtin_amdgcn_mfma_f32_16x16x32_bf16(al, bh, ACC[nt], 0,0,0); \
      ACC[nt] = __builtin_amdgcn_mfma_f32_16x16x32_bf16(ah, bo, ACC[nt], 0,0,0); \
    } \
  } \
} while(0)

// stage 64 node-rows of a (N,DIM) f32 global matrix into sA as bf16 hi/lo
#define STAGE_A(SRC) do { \
  const int row_  = tid >> 2; \
  const int kq_   = (tid & 3) * 16; \
  const int node_ = base + row_; \
  _Pragma("unroll") \
  for (int cc = 0; cc < 4; ++cc){ \
    float4 v = make_float4(0.f,0.f,0.f,0.f); \
    if (node_ < N_NODES) v = *(const float4*)&SRC[(size_t)node_*DIM + kq_ + 4*cc]; \
    unsigned short h_[4], l_[4]; \
    split2(v.x,h_[0],l_[0]); split2(v.y,h_[1],l_[1]); \
    split2(v.z,h_[2],l_[2]); split2(v.w,h_[3],l_[3]); \
    uint2 ph_, pl_; \
    ph_.x = (unsigned)h_[0] | ((unsigned)h_[1]<<16); \
    ph_.y = (unsigned)h_[2] | ((unsigned)h_[3]<<16); \
    pl_.x = (unsigned)l_[0] | ((unsigned)l_[1]<<16); \
    pl_.y = (unsigned)l_[2] | ((unsigned)l_[3]<<16); \
    *(uint2*)&sA[0][row_][kq_ + 4*cc] = ph_; \
    *(uint2*)&sA[1][row_][kq_ + 4*cc] = pl_; \
  } \
} while(0)

// =====================================================================
// MEGA (single kernel, 782 blocks, 3 fence-free barriers):
//   P0 scatter (csr32 via LLC atomic stores) -> bar0 ->
//   P1 mean for OWN 64-node tile -> LDS -> lin1 (hpre in regs),
//   stat partials -> replicated LLC atomics -> bar1 ->
//   P2 derive mu/inv, lin2 + fused attn pooling -> bar2 -> P3 head.
// LDS 37.9KB -> 4 blk/CU; launch_bounds(256,4) -> VGPR<=128.
// Capacity 4*256=1024 >= 782: all co-resident, barrier safe.
// =====================================================================
__global__ void __launch_bounds__(256, 4) k_mega(
    const int* __restrict__ ei, const float* __restrict__ x,
    const float* __restrict__ Wl, const float* __restrict__ bl,
    const float* __restrict__ Wr,
    const float* __restrict__ Wres, const float* __restrict__ bres,
    const float* __restrict__ gamma, const float* __restrict__ beta,
    const float* __restrict__ gW1, const float* __restrict__ gb1,
    const float* __restrict__ gW2, const float* __restrict__ gb2,
    const float* __restrict__ Wp1, const float* __restrict__ bp1,
    const float* __restrict__ Wp2, const float* __restrict__ bp2,
    const int* __restrict__ batch,
    int* __restrict__ cnt, unsigned* __restrict__ csr32,
    float* __restrict__ musum,
    float* __restrict__ zbuf, float* __restrict__ pooled,
    unsigned* __restrict__ bar, float* __restrict__ outp){
  __shared__ __align__(16) short sA[2][64][72];    // A tiles (x resident p1->p2)
  __shared__ __align__(16) short sB[2][64][72];    // weights / mean floats / scratch
  __shared__ int sb[64];
  __shared__ unsigned long long runmask;
  __shared__ float smu[2*DIM];
  __shared__ float psh[DIM];
  __shared__ float redh[4];

  const int tid  = threadIdx.x;
  const int lane = tid & 63, w = tid >> 6;
  const int jc   = lane & 15;
  const int g16  = w*4 + (lane >> 4);
  const int mrow = 16*w + jc;
  const int koff = (lane >> 4) * 8;
  const int r0   = 16*w + (lane >> 4)*4;  // == 4*g16
  const int bx   = blockIdx.x;
  const int base = bx * 64;

  // ================= P0: scatter (1024 edges/block, 4/thread) ==========
  {
    const int e0 = bx * EPB + tid;
    #pragma unroll
    for (int q = 0; q < 4; ++q){
      const int i = e0 + q*256;
      if (i < N_EDGES){
        int d = ei[N_EDGES + i];
        int s = ei[i];
        int pos = atomicAdd(&cnt[d], 1);
        ustore(&csr32[(size_t)pos*N_NODES + d], (unsigned)s);
      }
    }
  }
  gbar(bar, bx);

  // ================= P1: mean for own tile -> sBf ======================
  {
    float* sBf = (float*)&sB[0][0][0];       // 64x64 f32 overlay (16KB<=18.4KB)
    const int g = lane >> 4, f = lane & 15;
    for (int n16 = 0; n16 < 16; ++n16){
      const int row = w*16 + n16;
      const int node = base + row;
      const int dg = (node < N_NODES) ? iload(&cnt[node]) : 0;
      float4 a4 = make_float4(0.f,0.f,0.f,0.f);
      int e = 0;
      if (lane < dg) e = (int)uload(&csr32[(size_t)lane*N_NODES + node]);
      int i = 0;
      for (; i + 16 <= dg; i += 16){
        int s0 = __shfl(e, i +      g, 64);
        int s1 = __shfl(e, i + 4  + g, 64);
        int s2 = __shfl(e, i + 8  + g, 64);
        int s3 = __shfl(e, i + 12 + g, 64);
        float4 v0 = *(const float4*)&x[(size_t)s0*DIM + f*4];
        float4 v1 = *(const float4*)&x[(size_t)s1*DIM + f*4];
        float4 v2 = *(const float4*)&x[(size_t)s2*DIM + f*4];
        float4 v3 = *(const float4*)&x[(size_t)s3*DIM + f*4];
        a4.x += v0.x + v1.x + v2.x + v3.x;
        a4.y += v0.y + v1.y + v2.y + v3.y;
        a4.z += v0.z + v1.z + v2.z + v3.z;
        a4.w += v0.w + v1.w + v2.w + v3.w;
      }
      for (; i < dg; i += 4){
        int idx = i + g;
        int srcl = (idx < dg) ? idx : (dg - 1);   // clamp: valid-lane shfl
        int s = __shfl(e, srcl, 64);
        if (idx < dg){
          float4 v = *(const float4*)&x[(size_t)s*DIM + f*4];
          a4.x += v.x; a4.y += v.y; a4.z += v.z; a4.w += v.w;
        }
      }
      a4.x += __shfl_xor(a4.x, 16, 64); a4.x += __shfl_xor(a4.x, 32, 64);
      a4.y += __shfl_xor(a4.y, 16, 64); a4.y += __shfl_xor(a4.y, 32, 64);
      a4.z += __shfl_xor(a4.z, 16, 64); a4.z += __shfl_xor(a4.z, 32, 64);
      a4.w += __shfl_xor(a4.w, 16, 64); a4.w += __shfl_xor(a4.w, 32, 64);
      if (g == 0){
        float inv = 1.f / fmaxf((float)dg, 1.f);
        *(float4*)&sBf[row*64 + 4*f] =
          make_float4(a4.x*inv, a4.y*inv, a4.z*inv, a4.w*inv);
      }
    }
  }
  __syncthreads();                 // sBf complete

  // ================= lin1 =================
  float blv[4];
  #pragma unroll
  for (int nt = 0; nt < 4; ++nt) blv[nt] = bl[nt*16 + jc];

  f32x4 acc[4] = {};
  {
    // move mean (sBf) -> registers, then sA bf16 splits; stage Wl into sB
    float* sBf = (float*)&sB[0][0][0];
    const int row_ = tid >> 2;
    const int kq_  = (tid & 3) * 16;
    float4 mv[4];
    #pragma unroll
    for (int cc = 0; cc < 4; ++cc)
      mv[cc] = *(float4*)&sBf[row_*64 + kq_ + 4*cc];
    __syncthreads();               // done reading sBf; sB reusable
    #pragma unroll
    for (int cc = 0; cc < 4; ++cc){
      unsigned short h_[4], l_[4];
      split2(mv[cc].x,h_[0],l_[0]); split2(mv[cc].y,h_[1],l_[1]);
      split2(mv[cc].z,h_[2],l_[2]); split2(mv[cc].w,h_[3],l_[3]);
      uint2 ph_, pl_;
      ph_.x = (unsigned)h_[0] | ((unsigned)h_[1]<<16);
      ph_.y = (unsigned)h_[2] | ((unsigned)h_[3]<<16);
      pl_.x = (unsigned)l_[0] | ((unsigned)l_[1]<<16);
      pl_.y = (unsigned)l_[2] | ((unsigned)l_[3]<<16);
      *(uint2*)&sA[0][row_][kq_ + 4*cc] = ph_;
      *(uint2*)&sA[1][row_][kq_ + 4*cc] = pl_;
    }
    stage_w64(&sB[0][0][0], &sB[1][0][0], Wl, w, lane);
  }
  __syncthreads();
  GEMM64(acc);
  __syncthreads();
  stage_w64(&sB[0][0][0], &sB[1][0][0], Wr, w, lane);
  STAGE_A(x);                       // x split stays resident for lin2
  __syncthreads();
  GEMM64(acc);

  // epilogue: +bl, retain hpre in acc, stat partials
  float s1v[4] = {0.f,0.f,0.f,0.f}, s2v[4] = {0.f,0.f,0.f,0.f};
  #pragma unroll
  for (int nt = 0; nt < 4; ++nt){
    #pragma unroll
    for (int r = 0; r < 4; ++r){
      const int node = base + r0 + r;
      float v = acc[nt][r] + blv[nt];
      acc[nt][r] = v;
      if (node < N_NODES){ s1v[nt] += v; s2v[nt] += v*v; }
    }
  }
  __syncthreads();                  // all GEMM sB reads done
  {
    float* sred = (float*)&sB[0][0][0];   // 512-float scratch (sA keeps x)
    #pragma unroll
    for (int nt = 0; nt < 4; ++nt){
      float a = s1v[nt], b = s2v[nt];
      a += __shfl_xor(a, 16, 64); a += __shfl_xor(a, 32, 64);
      b += __shfl_xor(b, 16, 64); b += __shfl_xor(b, 32, 64);
      if ((lane >> 4) == 0){
        sred[0*256 + w*64 + nt*16 + jc] = a;
        sred[1*256 + w*64 + nt*16 + jc] = b;
      }
    }
    __syncthreads();
    const int rep = bx & (MREP-1);
    if (tid < 64){
      float a = sred[tid] + sred[64+tid] + sred[128+tid] + sred[192+tid];
      float b = sred[256+tid] + sred[320+tid] + sred[384+tid] + sred[448+tid];
      atomicAdd(&musum[(size_t)rep*128*MSTRIDE + (size_t)tid*MSTRIDE], a);
      atomicAdd(&musum[(size_t)rep*128*MSTRIDE + (size_t)(64+tid)*MSTRIDE], b);
    }
  }
  gbar(bar + BAR_STRIDE, bx);

  // ================= P2: derive mu/inv, lin2 + pooling =================
  if (tid < 64){
    float s1 = 0.f, s2 = 0.f;
    #pragma unroll
    for (int rep = 0; rep < MREP; ++rep){
      s1 += gload(&musum[(size_t)rep*128*MSTRIDE + (size_t)tid*MSTRIDE]);
      s2 += gload(&musum[(size_t)rep*128*MSTRIDE + (size_t)(64+tid)*MSTRIDE]);
    }
    float mu = s1 / (float)N_NODES;
    float var = s2 / (float)N_NODES - mu*mu;
    smu[tid] = mu;
    smu[DIM+tid] = 1.0f / sqrtf(var + EPSV);
  }
  if (tid < 64){
    int nn = base + tid;
    sb[tid] = batch[(nn < N_NODES) ? nn : (N_NODES-1)];
  }
  stage_w64(&sB[0][0][0], &sB[1][0][0], Wres, w, lane);
  __syncthreads();

  float muv[4], invv[4], gav[4], bev[4], brv[4], g1v[4], w2v[4];
  #pragma unroll
  for (int nt = 0; nt < 4; ++nt){
    const int col = nt*16 + jc;
    muv[nt] = smu[col];    invv[nt] = smu[DIM+col];
    gav[nt] = gamma[col];  bev[nt]  = beta[col];
    brv[nt] = bres[col];   g1v[nt]  = gb1[col];
    w2v[nt] = gW2[col];
  }
  const float gb2v = gb2[0];
  if (w == 0){
    bool fl = (lane > 0) && (sb[lane] != sb[lane-1]);
    unsigned long long mm = __ballot(fl);
    if (lane == 0) runmask = mm;
  }

  f32x4 acc2[4] = {};
  GEMM64(acc2);                     // x @ Wres (sA still holds x splits)

  // h2 = BN(hpre)+bres+acc2 -> acc ; splits into sA (own-wave rows)
  #pragma unroll
  for (int nt = 0; nt < 4; ++nt){
    const int col = nt*16 + jc;
    #pragma unroll
    for (int r = 0; r < 4; ++r){
      float v = (acc[nt][r] - muv[nt])*invv[nt]*gav[nt] + bev[nt]
              + brv[nt] + acc2[nt][r];
      acc[nt][r] = v;
      unsigned short hh, ll;
      split2(v, hh, ll);
      sA[0][r0 + r][col] = (short)hh;
      sA[1][r0 + r][col] = (short)ll;
    }
  }
  __syncthreads();                  // GEMM1 sB reads + h2 writes complete
  stage_w64(&sB[0][0][0], &sB[1][0][0], gW1, w, lane);
  __syncthreads();

  // GEMM2: h2 @ gW1
  f32x4 acc3[4] = {};
  GEMM64(acc3);

  // gate scalar per node -> e weights
  float p[4] = {0.f,0.f,0.f,0.f};
  #pragma unroll
  for (int nt = 0; nt < 4; ++nt){
    #pragma unroll
    for (int r = 0; r < 4; ++r)
      p[r] += fmaxf(acc3[nt][r] + g1v[nt], 0.f) * w2v[nt];
  }
  float ev[4];
  #pragma unroll
  for (int r = 0; r < 4; ++r){
    float t = p[r];
    t += __shfl_xor(t, 1, 64); t += __shfl_xor(t, 2, 64);
    t += __shfl_xor(t, 4, 64); t += __shfl_xor(t, 8, 64);
    const int node = base + r0 + r;
    ev[r] = (node < N_NODES) ? expf(t + gb2v) : 0.f;
  }

  // fused pooling: run-aware block reduce -> global atomics
  {
    float* sredp = (float*)&sA[0][0][0];
    float* szl   = sredp + 16*64;
    __syncthreads();                // GEMM2 sA reads complete
    const unsigned long long m = runmask;
    int rstart = 0;
    while (rstart < 64){
      const int bseg = sb[rstart];
      unsigned long long rest = (rstart >= 63) ? 0ull : (m >> (rstart+1));
      const int rend = rest ? (rstart + 1 + __builtin_ctzll(rest)) : 64;
      float pacc[4] = {0.f,0.f,0.f,0.f};
      float zacc = 0.f;
      #pragma unroll
      for (int r = 0; r < 4; ++r){
        const int ln = 4*g16 + r;
        if (ln >= rstart && ln < rend){
          #pragma unroll
          for (int nt = 0; nt < 4; ++nt) pacc[nt] += ev[r]*acc[nt][r];
          zacc += ev[r];
        }
      }
      #pragma unroll
      for (int nt = 0; nt < 4; ++nt) sredp[g16*64 + nt*16 + jc] = pacc[nt];
      if ((lane & 15) == 0) szl[g16] = zacc;
      __syncthreads();
      if (tid < 64){
        float s = 0.f;
        for (int g2 = 0; g2 < 16; ++g2) s += sredp[g2*64 + tid];
        atomicAdd(&pooled[bseg*DIM + tid], s);
      }
      if (tid == 64){
        float sz2 = 0.f;
        for (int g2 = 0; g2 < 16; ++g2) sz2 += szl[g2];
        atomicAdd(&zbuf[bseg], sz2);
      }
      __syncthreads();
      rstart = rend;
    }
  }
  gbar(bar + 2*BAR_STRIDE, bx);

  // ================= P3: head (blocks 0..127) =================
  if (bx < BATCHES){
    const int b = bx;
    const int t = tid;
    if (t < DIM){
      float zz = fmaxf(gload(&zbuf[b]), 1e-16f);
      psh[t] = gload(&pooled[b*DIM + t]) / zz;
    }
    __syncthreads();
    if (t < HID){
      float a = bp1[t];
      #pragma unroll
      for (int d2 = 0; d2 < DIM; ++d2) a = fmaf(psh[d2], Wp1[d2*HID + t], a);
      a = fmaxf(a, 0.f);
      float o0 = a * Wp2[t*NCLS+0];
      float o1 = a * Wp2[t*NCLS+1];
      #pragma unroll
      for (int o = 32; o > 0; o >>= 1){
        o0 += __shfl_down(o0, o, 64); o1 += __shfl_down(o1, o, 64);
      }
      int hw = t >> 6;
      if ((t & 63) == 0){ redh[hw*2+0] = o0; redh[hw*2+1] = o1; }
    }
    __syncthreads();
    if (t == 0){
      outp[b*NCLS+0] = redh[0]+redh[2]+bp2[0];
      outp[b*NCLS+1] = redh[1]+redh[3]+bp2[1];
    }
  }
}

extern "C" void kernel_launch(void* const* d_in, const int* in_sizes, int n_in,
                              void* d_out, int out_size, void* d_ws, size_t ws_size,
                              hipStream_t stream){
  const float* x     = (const float*)d_in[0];
  const int*   ei    = (const int*)d_in[1];
  const int*   batch = (const int*)d_in[2];
  const float* Wl    = (const float*)d_in[3];
  const float* bl    = (const float*)d_in[4];
  const float* Wr    = (const float*)d_in[5];
  const float* Wres  = (const float*)d_in[6];
  const float* bres  = (const float*)d_in[7];
  const float* gamma = (const float*)d_in[8];
  const float* beta  = (const float*)d_in[9];
  const float* gW1   = (const float*)d_in[10];
  const float* gb1   = (const float*)d_in[11];
  const float* gW2   = (const float*)d_in[12];
  const float* gb2   = (const float*)d_in[13];
  const float* Wp1   = (const float*)d_in[14];
  const float* bp1   = (const float*)d_in[15];
  const float* Wp2   = (const float*)d_in[16];
  const float* bp2   = (const float*)d_in[17];
  float* outp = (float*)d_out;

  // ---- workspace carve (zero-init region first, contiguous) ----
  int*      cnt    = (int*)d_ws;                        // N        (zeroed)
  float*    zbuf   = (float*)(cnt + N_NODES);           // B        (zeroed)
  float*    pooled = zbuf + BATCHES;                    // B*D      (zeroed)
  unsigned* bar    = (unsigned*)(pooled + (size_t)BATCHES*DIM); // 3*512 (zeroed)
  float*    musum  = (float*)(bar + 3*BAR_STRIDE);      // MREP*128*MSTRIDE (zeroed)
  unsigned* csr32  = (unsigned*)(musum + (size_t)MREP*128*MSTRIDE); // MAXD*N u32

  const size_t zcount = (size_t)N_NODES + BATCHES + (size_t)BATCHES*DIM
                      + 3*BAR_STRIDE + (size_t)MREP*128*MSTRIDE;
  hipMemsetAsync(d_ws, 0, zcount*sizeof(int), stream);

  k_mega<<<NBLK, 256, 0, stream>>>(ei, x, Wl, bl, Wr, Wres, bres,
                                   gamma, beta, gW1, gb1, gW2, gb2,
                                   Wp1, bp1, Wp2, bp2, batch,
                                   cnt, csr32, musum, zbuf, pooled, bar, outp);
}

// Round 7
// 193.554 us; speedup vs baseline: 1.0730x; 1.0730x over previous
//
#include <hip/hip_runtime.h>
#include <math.h>

#define N_NODES 50000
#define N_EDGES 800000
#define BATCHES 128
#define DIM 64
#define HID 128
#define NCLS 2
#define EPSV 1e-5f
#define MAXD 64                                   // padded CSR row stride

#define NPART 8
#define PART_SZ ((N_NODES + NPART - 1) / NPART)   // 6250
#define EPB 2048
#define NCHK_E ((N_EDGES + EPB - 1) / EPB)        // 391
#define NBLK 782                                  // mega grid: 1 tile/block

#define MREP 4                                    // stat accumulator replicas
#define MSTRIDE 32                                // floats between entries (128B)
#define BAR_STRIDE 512                            // uints per barrier struct (2KB)

typedef __attribute__((ext_vector_type(8))) short bf16x8;
typedef __attribute__((ext_vector_type(4))) float f32x4;

// ---- fp32 -> bf16 hi/lo split helpers ----
__device__ __forceinline__ unsigned short f2bf(float f){
  unsigned u = __float_as_uint(f);
  u += 0x7FFFu + ((u >> 16) & 1u);     // RNE
  return (unsigned short)(u >> 16);
}
__device__ __forceinline__ float bf2f(unsigned short h){
  return __uint_as_float(((unsigned)h) << 16);
}
__device__ __forceinline__ void split2(float f, unsigned short& hi, unsigned short& lo){
  hi = f2bf(f);
  lo = f2bf(f - bf2f(hi));
}
__device__ __forceinline__ uint4 pack8(const unsigned short* s){
  uint4 u;
  u.x = (unsigned)s[0] | ((unsigned)s[1] << 16);
  u.y = (unsigned)s[2] | ((unsigned)s[3] << 16);
  u.z = (unsigned)s[4] | ((unsigned)s[5] << 16);
  u.w = (unsigned)s[6] | ((unsigned)s[7] << 16);
  return u;
}

// ---- agent-scope (LLC-coherent) scalar access: cross-XCD safe ----
__device__ __forceinline__ float gload(const float* p){
  return __hip_atomic_load(p, __ATOMIC_RELAXED, __HIP_MEMORY_SCOPE_AGENT);
}

// ---- relaxed-only tree grid barrier: NO fences, NO L2 invalidates.
// All cross-barrier data moves via device-scope atomics (performed at LLC)
// and agent-scope atomic loads (LLC-direct), so cache flushes are not needed.
__device__ __forceinline__ void gbar(unsigned* bb, int bx){
  __syncthreads();                       // drains vmcnt: prior atomics ACKed @LLC
  if (threadIdx.x == 0){
    const int k = bx & 7;
    const unsigned quota = (k < (NBLK & 7)) ? (unsigned)(NBLK/8 + 1)
                                            : (unsigned)(NBLK/8);
    unsigned old = __hip_atomic_fetch_add(&bb[k*32], 1u,
                     __ATOMIC_RELAXED, __HIP_MEMORY_SCOPE_AGENT);
    if (old == quota - 1u){
      unsigned r = __hip_atomic_fetch_add(&bb[8*32], 1u,
                     __ATOMIC_RELAXED, __HIP_MEMORY_SCOPE_AGENT);
      if (r == 7u)
        __hip_atomic_store(&bb[9*32], 1u,
                     __ATOMIC_RELAXED, __HIP_MEMORY_SCOPE_AGENT);
    }
    while (__hip_atomic_load(&bb[9*32],
                     __ATOMIC_RELAXED, __HIP_MEMORY_SCOPE_AGENT) == 0u)
      __builtin_amdgcn_s_sleep(32);
  }
  asm volatile("" ::: "memory");         // compiler barrier (no instructions)
  __syncthreads();
}

// ---- K1: XCD-local partitioned scatter -> row-major ushort CSR + cnt.
// partition p = bx&7 matches the blockIdx->XCD round-robin, and owns node
// range [p*6250,(p+1)*6250): every csr row-line is written by ONE XCD's L2
// -> dirty set ~800KB/XCD (fits 4MB) -> ~1 writeback/line (~6MB total).
// Cost: 8x dense re-read of ei (51MB @ ~6TB/s ~ 9us) - a good trade vs
// 30MB of cross-XCD partial-line writebacks (R5: WRITE_SIZE 37MB).
__global__ void k_scatter(const int* __restrict__ ei, int* __restrict__ cnt,
                          unsigned short* __restrict__ csr){
  const int p = blockIdx.x & (NPART-1);
  const int c = blockIdx.x >> 3;
  const int lo = p * PART_SZ;
  const int hi = lo + PART_SZ;
  const int e0 = c * EPB;
  const int e1 = (e0 + EPB < N_EDGES) ? e0 + EPB : N_EDGES;
  for (int i = e0 + threadIdx.x; i < e1; i += 256){
    int d = ei[N_EDGES + i];
    if (d >= lo && d < hi){
      int s = ei[i];
      int pos = atomicAdd(&cnt[d], 1);
      csr[(size_t)d*MAXD + pos] = (unsigned short)s;
    }
  }
}

// ---- K2: per-node gather mean (row-major csr: contiguous 128B/node). ----
__global__ void k_mean(const float* __restrict__ x,
                       const unsigned short* __restrict__ csr,
                       const int* __restrict__ cnt, float* __restrict__ meanb){
  const int node = (blockIdx.x*256 + threadIdx.x) >> 6;
  const int lane = threadIdx.x & 63;
  const int g = lane >> 4, f = lane & 15;
  const int dg = cnt[node];
  const size_t start = (size_t)node * MAXD;
  float4 acc = make_float4(0.f,0.f,0.f,0.f);
  int e = (lane < dg) ? (int)csr[start + lane] : 0;
  int i = 0;
  for (; i + 16 <= dg; i += 16){
    int s0 = __shfl(e, i +      g, 64);
    int s1 = __shfl(e, i + 4  + g, 64);
    int s2 = __shfl(e, i + 8  + g, 64);
    int s3 = __shfl(e, i + 12 + g, 64);
    float4 v0 = *(const float4*)&x[(size_t)s0*DIM + f*4];
    float4 v1 = *(const float4*)&x[(size_t)s1*DIM + f*4];
    float4 v2 = *(const float4*)&x[(size_t)s2*DIM + f*4];
    float4 v3 = *(const float4*)&x[(size_t)s3*DIM + f*4];
    acc.x += v0.x + v1.x + v2.x + v3.x;
    acc.y += v0.y + v1.y + v2.y + v3.y;
    acc.z += v0.z + v1.z + v2.z + v3.z;
    acc.w += v0.w + v1.w + v2.w + v3.w;
  }
  for (; i < dg; i += 4){
    int idx = i + g;
    int srcl = (idx < dg) ? idx : (dg - 1);   // clamp: valid-lane shfl
    int s = __shfl(e, srcl, 64);
    if (idx < dg){
      float4 v = *(const float4*)&x[(size_t)s*DIM + f*4];
      acc.x += v.x; acc.y += v.y; acc.z += v.z; acc.w += v.w;
    }
  }
  acc.x += __shfl_xor(acc.x, 16, 64); acc.x += __shfl_xor(acc.x, 32, 64);
  acc.y += __shfl_xor(acc.y, 16, 64); acc.y += __shfl_xor(acc.y, 32, 64);
  acc.z += __shfl_xor(acc.z, 16, 64); acc.z += __shfl_xor(acc.z, 32, 64);
  acc.w += __shfl_xor(acc.w, 16, 64); acc.w += __shfl_xor(acc.w, 32, 64);
  if (g == 0){
    float inv = 1.f / fmaxf((float)dg, 1.f);
    float4 r = make_float4(acc.x*inv, acc.y*inv, acc.z*inv, acc.w*inv);
    *(float4*)&meanb[(size_t)node*DIM + f*4] = r;
  }
}

// helper: stage one 64x64 weight transposed as bf16 hi/lo into [64][72] rows
__device__ __forceinline__ void stage_w64(short* sWh, short* sWl_,
                                          const float* __restrict__ W,
                                          int w, int lane){
  const int k0 = 16 * w;
  #pragma unroll
  for (int kc = 0; kc < 2; ++kc){
    unsigned short h[8], l[8];
    #pragma unroll
    for (int i = 0; i < 8; ++i){
      int k = k0 + 8*kc + i;
      split2(W[k*DIM + lane], h[i], l[i]);
    }
    *(uint4*)&sWh[lane*72 + k0 + 8*kc] = pack8(h);
    *(uint4*)&sWl_[lane*72 + k0 + 8*kc] = pack8(l);
  }
}

// 64-wide-K split-bf16 GEMM: ACC += A(64x64 from sA) @ B(64x64 from sB)^T
#define GEMM64(ACC) do { \
  _Pragma("unroll") \
  for (int kt2 = 0; kt2 < 2; ++kt2){ \
    const int ka = kt2*32 + koff; \
    bf16x8 ah = *(const bf16x8*)&sA[0][mrow][ka]; \
    bf16x8 al = *(const bf16x8*)&sA[1][mrow][ka]; \
    _Pragma("unroll") \
    for (int nt = 0; nt < 4; ++nt){ \
      const int nr = nt*16 + jc; \
      bf16x8 bh = *(const bf16x8*)&sB[0][nr][ka]; \
      bf16x8 bo = *(const bf16x8*)&sB[1][nr][ka]; \
      ACC[nt] = __builtin_amdgcn_mfma_f32_16x16x32_bf16(ah, bh, ACC[nt], 0,0,0); \
      ACC[nt] = __builtin_amdgcn_mfma_f32_16x16x32_bf16(al, bh, ACC[nt], 0,0,0); \
      ACC[nt] = __builtin_amdgcn_mfma_f32_16x16x32_bf16(ah, bo, ACC[nt], 0,0,0); \
    } \
  } \
} while(0)

// stage 64 node-rows of a (N,DIM) f32 matrix into sA as bf16 hi/lo
#define STAGE_A(SRC) do { \
  const int row_  = tid >> 2; \
  const int kq_   = (tid & 3) * 16; \
  const int node_ = base + row_; \
  _Pragma("unroll") \
  for (int cc = 0; cc < 4; ++cc){ \
    float4 v = make_float4(0.f,0.f,0.f,0.f); \
    if (node_ < N_NODES) v = *(const float4*)&SRC[(size_t)node_*DIM + kq_ + 4*cc]; \
    unsigned short h_[4], l_[4]; \
    split2(v.x,h_[0],l_[0]); split2(v.y,h_[1],l_[1]); \
    split2(v.z,h_[2],l_[2]); split2(v.w,h_[3],l_[3]); \
    uint2 ph_, pl_; \
    ph_.x = (unsigned)h_[0] | ((unsigned)h_[1]<<16); \
    ph_.y = (unsigned)h_[2] | ((unsigned)h_[3]<<16); \
    pl_.x = (unsigned)l_[0] | ((unsigned)l_[1]<<16); \
    pl_.y = (unsigned)l_[2] | ((unsigned)l_[3]<<16); \
    *(uint2*)&sA[0][row_][kq_ + 4*cc] = ph_; \
    *(uint2*)&sA[1][row_][kq_ + 4*cc] = pl_; \
  } \
} while(0)

// =====================================================================
// MEGA: 782 single-tile blocks, LDS 37.9KB -> 4 blk/CU, VGPR<=128 ->
// capacity 1024 >= 782 co-resident. Two fence-free tree grid barriers.
// =====================================================================
__global__ void __launch_bounds__(256, 4) k_mega(
    const float* __restrict__ meanb, const float* __restrict__ x,
    const float* __restrict__ Wl, const float* __restrict__ bl,
    const float* __restrict__ Wr,
    const float* __restrict__ Wres, const float* __restrict__ bres,
    const float* __restrict__ gamma, const float* __restrict__ beta,
    const float* __restrict__ gW1, const float* __restrict__ gb1,
    const float* __restrict__ gW2, const float* __restrict__ gb2,
    const float* __restrict__ Wp1, const float* __restrict__ bp1,
    const float* __restrict__ Wp2, const float* __restrict__ bp2,
    const int* __restrict__ batch,
    float* __restrict__ musum,
    float* __restrict__ zbuf, float* __restrict__ pooled,
    unsigned* __restrict__ bar, float* __restrict__ outp){
  __shared__ __align__(16) short sA[2][64][72];    // A tiles (x resident p1->p3)
  __shared__ __align__(16) short sB[2][64][72];    // weight tile / stats scratch
  __shared__ int sb[64];
  __shared__ unsigned long long runmask;
  __shared__ float smu[2*DIM];
  __shared__ float psh[DIM];
  __shared__ float redh[4];

  const int tid  = threadIdx.x;
  const int lane = tid & 63, w = tid >> 6;
  const int jc   = lane & 15;
  const int g16  = w*4 + (lane >> 4);
  const int mrow = 16*w + jc;
  const int koff = (lane >> 4) * 8;
  const int r0   = 16*w + (lane >> 4)*4;  // == 4*g16
  const int bx   = blockIdx.x;
  const int base = bx * 64;

  // ================= phase 1: lin1 =================
  float blv[4];
  #pragma unroll
  for (int nt = 0; nt < 4; ++nt) blv[nt] = bl[nt*16 + jc];

  f32x4 acc[4] = {};
  stage_w64(&sB[0][0][0], &sB[1][0][0], Wl, w, lane);
  STAGE_A(meanb);
  __syncthreads();
  GEMM64(acc);
  __syncthreads();
  stage_w64(&sB[0][0][0], &sB[1][0][0], Wr, w, lane);
  STAGE_A(x);                       // x split stays resident for phase 3
  __syncthreads();
  GEMM64(acc);

  // epilogue: +bl, retain hpre in acc, stat partials
  float s1v[4] = {0.f,0.f,0.f,0.f}, s2v[4] = {0.f,0.f,0.f,0.f};
  #pragma unroll
  for (int nt = 0; nt < 4; ++nt){
    #pragma unroll
    for (int r = 0; r < 4; ++r){
      const int node = base + r0 + r;
      float v = acc[nt][r] + blv[nt];
      acc[nt][r] = v;
      if (node < N_NODES){ s1v[nt] += v; s2v[nt] += v*v; }
    }
  }
  __syncthreads();                  // all GEMM sB reads done
  {
    float* sred = (float*)&sB[0][0][0];   // 512-float scratch in sB (sA keeps x)
    #pragma unroll
    for (int nt = 0; nt < 4; ++nt){
      float a = s1v[nt], b = s2v[nt];
      a += __shfl_xor(a, 16, 64); a += __shfl_xor(a, 32, 64);
      b += __shfl_xor(b, 16, 64); b += __shfl_xor(b, 32, 64);
      if ((lane >> 4) == 0){
        sred[0*256 + w*64 + nt*16 + jc] = a;
        sred[1*256 + w*64 + nt*16 + jc] = b;
      }
    }
    __syncthreads();
    const int rep = bx & (MREP-1);
    if (tid < 64){
      float a = sred[tid] + sred[64+tid] + sred[128+tid] + sred[192+tid];
      float b = sred[256+tid] + sred[320+tid] + sred[384+tid] + sred[448+tid];
      atomicAdd(&musum[(size_t)rep*128*MSTRIDE + (size_t)tid*MSTRIDE], a);
      atomicAdd(&musum[(size_t)rep*128*MSTRIDE + (size_t)(64+tid)*MSTRIDE], b);
    }
  }
  gbar(bar, bx);

  // ================= phase 2: every block derives mu / inv-std =========
  if (tid < 64){
    float s1 = 0.f, s2 = 0.f;
    #pragma unroll
    for (int rep = 0; rep < MREP; ++rep){
      s1 += gload(&musum[(size_t)rep*128*MSTRIDE + (size_t)tid*MSTRIDE]);
      s2 += gload(&musum[(size_t)rep*128*MSTRIDE + (size_t)(64+tid)*MSTRIDE]);
    }
    float mu = s1 / (float)N_NODES;
    float var = s2 / (float)N_NODES - mu*mu;
    smu[tid] = mu;
    smu[DIM+tid] = 1.0f / sqrtf(var + EPSV);
  }
  if (tid < 64){
    int nn = base + tid;
    sb[tid] = batch[(nn < N_NODES) ? nn : (N_NODES-1)];
  }
  stage_w64(&sB[0][0][0], &sB[1][0][0], Wres, w, lane);
  __syncthreads();

  float muv[4], invv[4], gav[4], bev[4], brv[4], g1v[4], w2v[4];
  #pragma unroll
  for (int nt = 0; nt < 4; ++nt){
    const int col = nt*16 + jc;
    muv[nt] = smu[col];    invv[nt] = smu[DIM+col];
    gav[nt] = gamma[col];  bev[nt]  = beta[col];
    brv[nt] = bres[col];   g1v[nt]  = gb1[col];
    w2v[nt] = gW2[col];
  }
  const float gb2v = gb2[0];
  if (w == 0){
    bool fl = (lane > 0) && (sb[lane] != sb[lane-1]);
    unsigned long long mm = __ballot(fl);
    if (lane == 0) runmask = mm;
  }

  // ================= phase 3: lin2 + pooling =================
  f32x4 acc2[4] = {};
  GEMM64(acc2);

  // h2 = BN(hpre)+bres+acc2 -> acc ; splits into sA (own-wave rows)
  #pragma unroll
  for (int nt = 0; nt < 4; ++nt){
    const int col = nt*16 + jc;
    #pragma unroll
    for (int r = 0; r < 4; ++r){
      float v = (acc[nt][r] - muv[nt])*invv[nt]*gav[nt] + bev[nt]
              + brv[nt] + acc2[nt][r];
      acc[nt][r] = v;
      unsigned short hh, ll;
      split2(v, hh, ll);
      sA[0][r0 + r][col] = (short)hh;
      sA[1][r0 + r][col] = (short)ll;
    }
  }
  __syncthreads();                  // GEMM1 sB reads + h2 writes complete
  stage_w64(&sB[0][0][0], &sB[1][0][0], gW1, w, lane);
  __syncthreads();

  // GEMM2: h2 @ gW1
  f32x4 acc3[4] = {};
  GEMM64(acc3);

  // gate scalar per node -> e weights
  float p[4] = {0.f,0.f,0.f,0.f};
  #pragma unroll
  for (int nt = 0; nt < 4; ++nt){
    #pragma unroll
    for (int r = 0; r < 4; ++r)
      p[r] += fmaxf(acc3[nt][r] + g1v[nt], 0.f) * w2v[nt];
  }
  float ev[4];
  #pragma unroll
  for (int r = 0; r < 4; ++r){
    float t = p[r];
    t += __shfl_xor(t, 1, 64); t += __shfl_xor(t, 2, 64);
    t += __shfl_xor(t, 4, 64); t += __shfl_xor(t, 8, 64);
    const int node = base + r0 + r;
    ev[r] = (node < N_NODES) ? expf(t + gb2v) : 0.f;
  }

  // fused pooling: run-aware block reduce -> global atomics
  {
    float* sredp = (float*)&sA[0][0][0];
    float* szl   = sredp + 16*64;
    __syncthreads();                // GEMM2 sA reads complete
    const unsigned long long m = runmask;
    int rstart = 0;
    while (rstart < 64){
      const int bseg = sb[rstart];
      unsigned long long rest = (rstart >= 63) ? 0ull : (m >> (rstart+1));
      const int rend = rest ? (rstart + 1 + __builtin_ctzll(rest)) : 64;
      float pacc[4] = {0.f,0.f,0.f,0.f};
      float zacc = 0.f;
      #pragma unroll
      for (int r = 0; r < 4; ++r){
        const int ln = 4*g16 + r;
        if (ln >= rstart && ln < rend){
          #pragma unroll
          for (int nt = 0; nt < 4; ++nt) pacc[nt] += ev[r]*acc[nt][r];
          zacc += ev[r];
        }
      }
      #pragma unroll
      for (int nt = 0; nt < 4; ++nt) sredp[g16*64 + nt*16 + jc] = pacc[nt];
      if ((lane & 15) == 0) szl[g16] = zacc;
      __syncthreads();
      if (tid < 64){
        float s = 0.f;
        for (int g2 = 0; g2 < 16; ++g2) s += sredp[g2*64 + tid];
        atomicAdd(&pooled[bseg*DIM + tid], s);
      }
      if (tid == 64){
        float sz2 = 0.f;
        for (int g2 = 0; g2 < 16; ++g2) sz2 += szl[g2];
        atomicAdd(&zbuf[bseg], sz2);
      }
      __syncthreads();
      rstart = rend;
    }
  }
  gbar(bar + BAR_STRIDE, bx);

  // ================= phase 4: head (blocks 0..127) =================
  if (bx < BATCHES){
    const int b = bx;
    const int t = tid;
    if (t < DIM){
      float zz = fmaxf(gload(&zbuf[b]), 1e-16f);
      psh[t] = gload(&pooled[b*DIM + t]) / zz;
    }
    __syncthreads();
    if (t < HID){
      float a = bp1[t];
      #pragma unroll
      for (int d2 = 0; d2 < DIM; ++d2) a = fmaf(psh[d2], Wp1[d2*HID + t], a);
      a = fmaxf(a, 0.f);
      float o0 = a * Wp2[t*NCLS+0];
      float o1 = a * Wp2[t*NCLS+1];
      #pragma unroll
      for (int o = 32; o > 0; o >>= 1){
        o0 += __shfl_down(o0, o, 64); o1 += __shfl_down(o1, o, 64);
      }
      int hw = t >> 6;
      if ((t & 63) == 0){ redh[hw*2+0] = o0; redh[hw*2+1] = o1; }
    }
    __syncthreads();
    if (t == 0){
      outp[b*NCLS+0] = redh[0]+redh[2]+bp2[0];
      outp[b*NCLS+1] = redh[1]+redh[3]+bp2[1];
    }
  }
}

extern "C" void kernel_launch(void* const* d_in, const int* in_sizes, int n_in,
                              void* d_out, int out_size, void* d_ws, size_t ws_size,
                              hipStream_t stream){
  const float* x     = (const float*)d_in[0];
  const int*   ei    = (const int*)d_in[1];
  const int*   batch = (const int*)d_in[2];
  const float* Wl    = (const float*)d_in[3];
  const float* bl    = (const float*)d_in[4];
  const float* Wr    = (const float*)d_in[5];
  const float* Wres  = (const float*)d_in[6];
  const float* bres  = (const float*)d_in[7];
  const float* gamma = (const float*)d_in[8];
  const float* beta  = (const float*)d_in[9];
  const float* gW1   = (const float*)d_in[10];
  const float* gb1   = (const float*)d_in[11];
  const float* gW2   = (const float*)d_in[12];
  const float* gb2   = (const float*)d_in[13];
  const float* Wp1   = (const float*)d_in[14];
  const float* bp1   = (const float*)d_in[15];
  const float* Wp2   = (const float*)d_in[16];
  const float* bp2   = (const float*)d_in[17];
  float* outp = (float*)d_out;

  // ---- workspace carve (zero-init region first, contiguous) ----
  int*      cnt    = (int*)d_ws;                        // N        (zeroed)
  float*    zbuf   = (float*)(cnt + N_NODES);           // B        (zeroed)
  float*    pooled = zbuf + BATCHES;                    // B*D      (zeroed)
  unsigned* bar    = (unsigned*)(pooled + (size_t)BATCHES*DIM); // 2*512 (zeroed)
  float*    musum  = (float*)(bar + 2*BAR_STRIDE);      // MREP*128*MSTRIDE (zeroed)
  float*    meanb  = musum + (size_t)MREP*128*MSTRIDE;  // N*D
  unsigned short* csr = (unsigned short*)(meanb + (size_t)N_NODES*DIM); // N*MAXD u16

  const size_t zcount = (size_t)N_NODES + BATCHES + (size_t)BATCHES*DIM
                      + 2*BAR_STRIDE + (size_t)MREP*128*MSTRIDE;
  hipMemsetAsync(d_ws, 0, zcount*sizeof(int), stream);

  k_scatter<<<NPART*NCHK_E, 256, 0, stream>>>(ei, cnt, csr);
  k_mean   <<<N_NODES/4, 256, 0, stream>>>(x, csr, cnt, meanb);
  k_mega   <<<NBLK, 256, 0, stream>>>(meanb, x, Wl, bl, Wr, Wres, bres,
                                      gamma, beta, gW1, gb1, gW2, gb2,
                                      Wp1, bp1, Wp2, bp2, batch,
                                      musum, zbuf, pooled, bar, outp);
}